// Round 9
// baseline (3969.815 us; speedup 1.0000x reference)
//
#include <hip/hip_runtime.h>
#include <stdint.h>

#define DI __device__ __forceinline__

typedef __bf16 bf16;
typedef __bf16 bf16x8 __attribute__((ext_vector_type(8)));
typedef float  f32x4  __attribute__((ext_vector_type(4)));

// ---------------- problem constants ----------------
constexpr int Q = 256;
constexpr int BATCH = 65536;
constexpr int TM = 64;              // rows per block (4 waves x 16 rows)
constexpr int THREADS = 256;        // 4 waves; R15: each wave owns 16 rows end-to-end
constexpr int NW = 4;
constexpr int NBLK = BATCH / TM;    // 1024
constexpr int SC = Q + 8;           // LDS row stride (264 bf16 = 528 B, 16B-aligned)

// ---------------- workspace layout (packed bf16 weights, Wt[N][K] row-major) ----------------
constexpr int W0A_OFF = 0;                         // 3 x (768x256)
constexpr int W0B_OFF = W0A_OFF + 3*768*256;       // 3 x (256x768)
constexpr int W1A_OFF = W0B_OFF + 3*256*768;       // 3 x (512x256)
constexpr int W1B_OFF = W1A_OFF + 3*512*256;       // 3 x (256x512)
constexpr int WV_OFF  = W1B_OFF + 3*256*512;       // 2 x (256x256)  fusion input
constexpr int WO_OFF  = WV_OFF  + 2*65536;         // 2 x (256x256)  fusion input
constexpr int ATF_OFF = WO_OFF  + 2*65536;         // 2 x (256x256)  WVO = wv@wo (packed ^T)
constexpr int ENT_OFF = ATF_OFF + 2*65536;         // 8 x (256x256)  tanh pre-applied
constexpr int NL1_OFF = ENT_OFF + 8*65536;         // 4 x (256x256)
constexpr int NL2_OFF = NL1_OFF + 4*65536;         // 4 x (256x256)
constexpr int WEND    = NL2_OFF + 4*65536;
constexpr size_t F32_BYTE_OFF = (((size_t)WEND*2) + 255) & ~(size_t)255;

// f32 param region (element offsets)
constexpr int P_D0B1 = 0;                  // 3*768
constexpr int P_LNW  = P_D0B1 + 3*768;
constexpr int P_LNB  = P_LNW  + 3*768;
constexpr int P_D0B2 = P_LNB  + 3*768;     // 3*256
constexpr int P_D1B1 = P_D0B2 + 3*256;     // 3*512
constexpr int P_D1B2 = P_D1B1 + 3*512;     // 3*256
constexpr int P_BQV  = P_D1B2 + 3*256;     // 2*256
constexpr int P_BO   = P_BQV  + 2*256;     // 2*256
constexpr int P_NB1  = P_BO   + 2*256;     // 4*256
constexpr int P_NB2  = P_NB1  + 4*256;     // 4*256
constexpr int P_GLIN = P_NB2  + 4*256;     // 8*256
constexpr int P_GP3  = P_GLIN + 8*256;
constexpr int P_GP4  = P_GP3  + 8*256;
constexpr int P_GP5  = P_GP4  + 8*256;
constexpr int P_PACK_END = P_GP5 + 8*256;  // 21,248 (filled by pack_params)
constexpr int P_BAT  = P_PACK_END;         // 2*256  fused attn bias (bqv@wo + bo)
constexpr int P_TOT  = P_BAT + 2*256;
constexpr size_t FLAG_OFF = F32_BYTE_OFF + (size_t)P_TOT*4;   // one int

// ---------------- dual-dtype load helper ----------------
DI float ldf(const void* p, size_t idx, int f32) {
  return f32 ? ((const float*)p)[idx] : (float)((const bf16*)p)[idx];
}

// ---------------- device math helpers ----------------
DI float tanh_fast(float x) {
  float ax = fabsf(x);
  float e  = __expf(-2.0f * ax);
  float r  = (1.0f - e) / (1.0f + e);
  return copysignf(r, x);
}

DI float gelu_f(float x) {   // exact-gelu via A&S 7.1.26 erf
  float ax = fabsf(x) * 0.70710678118654752f;
  float t  = 1.0f / (1.0f + 0.3275911f * ax);
  float y  = t*(0.254829592f + t*(-0.284496736f + t*(1.421413741f +
             t*(-1.453152027f + t*1.061405429f))));
  float er = copysignf(1.0f - y * __expf(-ax*ax), x);
  return 0.5f * x * (1.0f + er);
}

DI f32x4 mfma_bf16(uint4 a, uint4 b, f32x4 c) {
  return __builtin_amdgcn_mfma_f32_16x16x32_bf16(
      __builtin_bit_cast(bf16x8, a), __builtin_bit_cast(bf16x8, b), c, 0, 0, 0);
}

DI void zero16(f32x4 (&a)[16]) {
#pragma unroll
  for (int j = 0; j < 16; ++j) a[j] = f32x4{0.f, 0.f, 0.f, 0.f};
}

// ---- per-wave GEMM: out(16 rows x 256 cols) += A(16x256, regs) * Bt[N][KDB] k-chunk ----
// A-frag: aA[kk] = A[row=l16][k = quad*8 + kk*32 .. +8].  acc C-layout: tile nj,
// col = nj*16 + l16, row = quad*4 + reg.
template<int KDB>
DI void gemm16(const uint4 (&aA)[8], const bf16* __restrict__ Bt, int koff,
               f32x4 (&acc)[16], int quad, int l16) {
  const bf16* bp = Bt + (size_t)l16*KDB + koff + quad*8;
#pragma unroll
  for (int kk = 0; kk < 8; ++kk)
#pragma unroll
    for (int nj = 0; nj < 16; ++nj) {
      uint4 bv = *(const uint4*)(bp + (size_t)(nj*16)*KDB + kk*32);
      acc[nj] = mfma_bf16(aA[kk], bv, acc[nj]);
    }
}

// reversed-kk variant (anti-CSE vs forward call: dense0 stats pass)
template<int KDB>
DI void gemm16r(const uint4 (&aA)[8], const bf16* __restrict__ Bt, int koff,
                f32x4 (&acc)[16], int quad, int l16) {
  const bf16* bp = Bt + (size_t)l16*KDB + koff + quad*8;
#pragma unroll
  for (int kk = 7; kk >= 0; --kk)
#pragma unroll
    for (int nj = 0; nj < 16; ++nj) {
      uint4 bv = *(const uint4*)(bp + (size_t)(nj*16)*KDB + kk*32);
      acc[nj] = mfma_bf16(aA[kk], bv, acc[nj]);
    }
}

// load A-fragments (8 x uint4) from a wave-private [16][SC] bf16 buffer
DI void loadA(uint4 (&aA)[8], const bf16* buf, int quad, int l16) {
  const bf16* p = buf + l16*SC + quad*8;
#pragma unroll
  for (int kk = 0; kk < 8; ++kk) aA[kk] = *(const uint4*)(p + kk*32);
}

// store C-layout acc into wave-private [16][SC] bf16 buffer
DI void storeC(bf16* buf, const f32x4 (&a)[16], int quad, int l16) {
#pragma unroll
  for (int nj = 0; nj < 16; ++nj) {
    int col = nj*16 + l16;
#pragma unroll
    for (int reg = 0; reg < 4; ++reg)
      buf[(quad*4 + reg)*SC + col] = (bf16)a[nj][reg];
  }
}

DI void addbias16(f32x4 (&a)[16], const float* __restrict__ b, int l16) {
#pragma unroll
  for (int nj = 0; nj < 16; ++nj) {
    float bb = b[nj*16 + l16];
#pragma unroll
    for (int reg = 0; reg < 4; ++reg) a[nj][reg] += bb;
  }
}

// ---------------- dtype detector ----------------
__global__ void detect_dtype(const uint16_t* __restrict__ xr, int* __restrict__ flag) {
  __shared__ int s_max;
  if (threadIdx.x == 0) s_max = 0;
  __syncthreads();
  int e = 0;
  for (int i = threadIdx.x; i < 4096; i += 256) {
    int ex = (xr[2*i] >> 7) & 0xFF;
    e = e > ex ? e : ex;
  }
  atomicMax(&s_max, e);
  __syncthreads();
  if (threadIdx.x == 0) *flag = (s_max >= 140) ? 1 : 0;
}

// ---------------- weight repack: W(KxN) -> Wt(NxK) bf16, optional tanh ----------------
__global__ void pack_weights(const void* __restrict__ d0w1, const void* __restrict__ d0w2,
                             const void* __restrict__ d1w1, const void* __restrict__ d1w2,
                             const void* __restrict__ wqkv, const void* __restrict__ wo,
                             const void* __restrict__ ent,  const void* __restrict__ nl1,
                             const void* __restrict__ nl2,  bf16* __restrict__ wsb,
                             const int* __restrict__ flag) {
  const int f32 = *flag;
  int job = blockIdx.y;
  const void* src; int mi, K, N, srcN, col0 = 0, dtanh = 0; long dst;
  if      (job < 3)  { src=d0w1; mi=job;    K=256; N=768; srcN=768; dst=W0A_OFF + (long)mi*768*256; }
  else if (job < 6)  { src=d0w2; mi=job-3;  K=768; N=256; srcN=256; dst=W0B_OFF + (long)mi*256*768; }
  else if (job < 9)  { src=d1w1; mi=job-6;  K=256; N=512; srcN=512; dst=W1A_OFF + (long)mi*512*256; }
  else if (job < 12) { src=d1w2; mi=job-9;  K=512; N=256; srcN=256; dst=W1B_OFF + (long)mi*256*512; }
  else if (job < 14) { src=wqkv; mi=job-12; K=256; N=256; srcN=768; col0=512; dst=WV_OFF + (long)mi*65536; }
  else if (job < 16) { src=wo;   mi=job-14; K=256; N=256; srcN=256; dst=WO_OFF + (long)mi*65536; }
  else if (job < 24) { src=ent;  mi=job-16; K=256; N=256; srcN=256; dst=ENT_OFF + (long)mi*65536; dtanh=1; }
  else if (job < 28) { src=nl1;  mi=job-24; K=256; N=256; srcN=256; dst=NL1_OFF + (long)mi*65536; }
  else               { src=nl2;  mi=job-28; K=256; N=256; srcN=256; dst=NL2_OFF + (long)mi*65536; }
  const size_t base = (size_t)mi * K * srcN;

  int tk = K/64, tn = N/64;
  int tile = blockIdx.x;
  if (tile >= tk*tn) return;
  int ik = tile % tk, in_ = tile / tk;

  __shared__ float t[64][65];
  int tid = threadIdx.x;
  for (int e = tid; e < 4096; e += 256) {
    int r = e >> 6, c = e & 63;
    t[r][c] = ldf(src, base + (size_t)(ik*64 + r)*srcN + col0 + in_*64 + c, f32);
  }
  __syncthreads();
  for (int e = tid; e < 4096; e += 256) {
    int nr = e >> 6, kc = e & 63;
    float v = t[kc][nr];
    if (dtanh) v = tanhf(v);
    wsb[dst + (size_t)(in_*64 + nr)*K + ik*64 + kc] = (bf16)v;
  }
}

// ---------------- param repack ----------------
__global__ void pack_params(const void* __restrict__ d0b1, const void* __restrict__ lnw,
                            const void* __restrict__ lnb,  const void* __restrict__ d0b2,
                            const void* __restrict__ d1b1, const void* __restrict__ d1b2,
                            const void* __restrict__ bqkv, const void* __restrict__ bo,
                            const void* __restrict__ gp,   const void* __restrict__ nb1,
                            const void* __restrict__ nb2,  float* __restrict__ wsf,
                            const int* __restrict__ flag) {
  const int f32 = *flag;
  int i = blockIdx.x * blockDim.x + threadIdx.x;
  if (i >= P_PACK_END) return;
  float v;
  if      (i < P_LNW)  { v = ldf(d0b1, i - P_D0B1, f32); }
  else if (i < P_LNB)  { v = ldf(lnw, i - P_LNW, f32); }
  else if (i < P_D0B2) { v = ldf(lnb, i - P_LNB, f32); }
  else if (i < P_D1B1) { v = ldf(d0b2, i - P_D0B2, f32); }
  else if (i < P_D1B2) { v = ldf(d1b1, i - P_D1B1, f32); }
  else if (i < P_BQV)  { v = ldf(d1b2, i - P_D1B2, f32); }
  else if (i < P_BO)   { int k = i - P_BQV; v = ldf(bqkv, (size_t)(k >> 8)*768 + 512 + (k & 255), f32); }
  else if (i < P_NB1)  { v = ldf(bo, i - P_BO, f32); }
  else if (i < P_NB2)  { v = ldf(nb1, i - P_NB1, f32); }
  else if (i < P_GLIN) { v = ldf(nb2, i - P_NB2, f32); }
  else if (i < P_GP3)  { int k = i - P_GLIN;
                         v = sinf(ldf(gp, (size_t)k*6 + 0, f32)) +
                             cosf(ldf(gp, (size_t)k*6 + 1, f32)) +
                             tanhf(ldf(gp, (size_t)k*6 + 2, f32)); }
  else if (i < P_GP4)  { int k = i - P_GP3; v = ldf(gp, (size_t)k*6 + 3, f32); }
  else if (i < P_GP5)  { int k = i - P_GP4; v = ldf(gp, (size_t)k*6 + 4, f32); }
  else                 { int k = i - P_GP5; v = ldf(gp, (size_t)k*6 + 5, f32); }
  wsf[i] = v;
}

// ---------------- WVO builder: ATF^T[c][m] = (wv@wo)[m][c] = sum_n wo[n][c]*wv[m][n] ----
__global__ void fuse_gemm(bf16* __restrict__ wsb) {
  int i = blockIdx.z;
  const bf16* A = wsb + WO_OFF + (size_t)i*65536;
  const bf16* B = wsb + WV_OFF + (size_t)i*65536;
  bf16* C = wsb + ATF_OFF + (size_t)i*65536;
  int m = threadIdx.x;
  int c = blockIdx.y;
  float s = 0.f;
  for (int n = 0; n < 256; ++n) s += (float)A[c*256 + n] * (float)B[(size_t)n*256 + m];
  C[(size_t)c*256 + m] = (bf16)s;
}

// ---------------- fused attn bias: P_BAT[i][c] = sum_m bqv[i][m]*woT[i][c][m] + bo[i][c] ----
__global__ void fuse_bias(const bf16* __restrict__ wsb, float* __restrict__ wsf) {
  int t = blockIdx.x * blockDim.x + threadIdx.x;
  if (t >= 512) return;
  int i = t >> 8, c = t & 255;
  const float* bqv = wsf + P_BQV + i*256;
  const bf16* woT = wsb + WO_OFF + (size_t)i*65536;
  float s = wsf[P_BO + i*256 + c];
  for (int m = 0; m < 256; ++m) s += bqv[m] * (float)woT[c*256 + m];
  wsf[P_BAT + i*256 + c] = s;
}

// ---------------- fused 8-layer forward: ZERO-BARRIER, wave-owns-rows ----------------
// R15: each wave owns 16 COMPLETE rows end-to-end. All reductions (LN, L2-norm)
// are per-row -> intra-wave shfl butterflies with lane-local results. All
// acc->A-frag transposes go through WAVE-PRIVATE LDS (in-order per-wave DS,
// lgkmcnt only). There is NO __syncthreads in this kernel: 8 independent
// wave-chains per CU interleave MFMA/VALU/load latency freely, removing the
// whole-CU barrier lockstep that R6-R14 could not break (R14 null: co-resident
// blocks phase-lock; barrier domains don't help - wave independence does).
__global__ __launch_bounds__(THREADS, 2)
void vqc_main(const void* __restrict__ x, const bf16* __restrict__ wsb,
              const float* __restrict__ wsf, const int* __restrict__ flag,
              void* __restrict__ out) {
  __shared__ __align__(16) bf16 curW_all[NW*16*SC];   // per-wave cur (C-layout)
  __shared__ __align__(16) bf16 scr_all[NW*16*SC];    // per-wave transpose scratch

  const int tid  = threadIdx.x;
  const int wave = tid >> 6, lane = tid & 63;
  const int quad = lane >> 4, l16 = lane & 15;
  bf16* curW = curW_all + wave*16*SC;
  bf16* scr  = scr_all  + wave*16*SC;
  const size_t wrow = (size_t)blockIdx.x * TM + wave*16;   // first of my 16 rows
  const int f32io = *flag;

  // ---- load my 16 rows into curW (C-layout [row][col]) ----
  if (f32io) {
    const float* xf = (const float*)x;
#pragma unroll
    for (int it = 0; it < 16; ++it) {
      int idx = it*64 + lane;               // 0..1023
      int row = idx >> 6, col = (idx & 63) * 4;
      const float* s = xf + (wrow + row)*Q + col;
      bf16* d = curW + row*SC + col;
      d[0] = (bf16)s[0]; d[1] = (bf16)s[1]; d[2] = (bf16)s[2]; d[3] = (bf16)s[3];
    }
  } else {
    const bf16* xb = (const bf16*)x;
#pragma unroll
    for (int it = 0; it < 8; ++it) {
      int idx = it*64 + lane;               // 0..511
      int row = idx >> 5, col = (idx & 31) * 8;
      *(uint4*)(curW + row*SC + col) = *(const uint4*)(xb + (wrow + row)*Q + col);
    }
  }
  uint4 curA[8];
  loadA(curA, curW, quad, l16);             // lgkmcnt-ordered, same wave

#pragma unroll 1
  for (int li = 0; li < 8; ++li) {
    const int t = li % 3;
    f32x4 acc2[16];                         // cur_new, col = nj*16+l16, row = quad*4+reg

    if (t == 0) {
      // ---- dense0: h = gelu(LN(cur@w1+b1)); cur_new = h@w2+b2 (two-pass LN) ----
      const int i = li / 3;
      const bf16* w1 = wsb + W0A_OFF + (size_t)i*768*256;
      const bf16* w2 = wsb + W0B_OFF + (size_t)i*256*768;
      const float* b1 = wsf + P_D0B1 + i*768;

      // Pass 1: LN stats; h chunks discarded
      float sa4[4], sb4[4];
#pragma unroll
      for (int reg = 0; reg < 4; ++reg) { sa4[reg] = 0.f; sb4[reg] = 0.f; }
#pragma unroll 1
      for (int c = 0; c < 3; ++c) {
        f32x4 ah[16]; zero16(ah);
        gemm16r<256>(curA, w1 + (size_t)c*256*256, 0, ah, quad, l16);
#pragma unroll
        for (int nj = 0; nj < 16; ++nj) {
          float bb = b1[c*256 + nj*16 + l16];
#pragma unroll
          for (int reg = 0; reg < 4; ++reg) {
            float v = ah[nj][reg] + bb;
            sa4[reg] += v; sb4[reg] += v*v;
          }
        }
      }
      float mu[4], rs[4];
#pragma unroll
      for (int reg = 0; reg < 4; ++reg) {
        float sa = sa4[reg], sb = sb4[reg];
#pragma unroll
        for (int m = 1; m < 16; m <<= 1) { sa += __shfl_xor(sa, m, 64); sb += __shfl_xor(sb, m, 64); }
        float mm = sa * (1.0f/768.0f);
        float var = sb * (1.0f/768.0f) - mm*mm;
        mu[reg] = mm; rs[reg] = rsqrtf(fmaxf(var, 0.f) + 1e-5f);
      }

      // Pass 2: recompute chunk, LN+gelu -> scr, chunked GEMM2 accumulate
      zero16(acc2);
#pragma unroll 1
      for (int c = 0; c < 3; ++c) {
        f32x4 ah[16]; zero16(ah);
        gemm16<256>(curA, w1 + (size_t)c*256*256, 0, ah, quad, l16);
        const float* lw = wsf + P_LNW + i*768 + c*256;
        const float* lb = wsf + P_LNB + i*768 + c*256;
#pragma unroll
        for (int nj = 0; nj < 16; ++nj) {
          int col = nj*16 + l16;
          float bb = b1[c*256 + col];
          float w_ = lw[col], lbb = lb[col];
#pragma unroll
          for (int reg = 0; reg < 4; ++reg) {
            float h = gelu_f((ah[nj][reg] + bb - mu[reg]) * rs[reg] * w_ + lbb);
            scr[(quad*4 + reg)*SC + col] = (bf16)h;
          }
        }
        uint4 hA[8];
        loadA(hA, scr, quad, l16);
        gemm16<768>(hA, w2, c*256, acc2, quad, l16);
      }
      addbias16(acc2, wsf + P_D0B2 + i*256, l16);
    } else if (t == 1) {
      // ---- dense1: cur_new = silu(cur@w1+b1)@w2 + b2, chunk-fused ----
      const int i = (li - 1) / 3;
      const bf16* w1 = wsb + W1A_OFF + (size_t)i*512*256;
      const bf16* w2 = wsb + W1B_OFF + (size_t)i*256*512;
      const float* b1 = wsf + P_D1B1 + i*512;
      zero16(acc2);
#pragma unroll 1
      for (int c = 0; c < 2; ++c) {
        f32x4 ah[16]; zero16(ah);
        gemm16<256>(curA, w1 + (size_t)c*256*256, 0, ah, quad, l16);
#pragma unroll
        for (int nj = 0; nj < 16; ++nj) {
          int col = nj*16 + l16;
          float bb = b1[c*256 + col];
#pragma unroll
          for (int reg = 0; reg < 4; ++reg) {
            float xv = ah[nj][reg] + bb;
            scr[(quad*4 + reg)*SC + col] = (bf16)(xv / (1.0f + __expf(-xv)));
          }
        }
        uint4 hA[8];
        loadA(hA, scr, quad, l16);
        gemm16<512>(hA, w2, c*256, acc2, quad, l16);
      }
      addbias16(acc2, wsf + P_D1B2 + i*256, l16);
    } else {
      // ---- attn (collapsed): cur_new = cur@WVO + bat ----
      const int i = (li - 2) / 3;
      zero16(acc2);
      gemm16<256>(curA, wsb + ATF_OFF + (size_t)i*65536, 0, acc2, quad, l16);
      addbias16(acc2, wsf + P_BAT + i*256, l16);
    }

    // ---- entangled: acc3 = cur_new @ tanhE ----
    storeC(scr, acc2, quad, l16);
    uint4 eA[8];
    loadA(eA, scr, quad, l16);
    f32x4 acc3[16]; zero16(acc3);
    gemm16<256>(eA, wsb + ENT_OFF + (size_t)li*65536, 0, acc3, quad, l16);

    // ---- gate + entangled combine ----
    {
      const float* gl = wsf + P_GLIN + li*256;
      const float* g3 = wsf + P_GP3  + li*256;
      const float* g4 = wsf + P_GP4  + li*256;
      const float* g5 = wsf + P_GP5  + li*256;
#pragma unroll
      for (int nj = 0; nj < 16; ++nj) {
        int col = nj*16 + l16;
        float lin = gl[col], p3 = g3[col], p4 = g4[col], p5 = g5[col];
#pragma unroll
        for (int reg = 0; reg < 4; ++reg) {
          float v = acc2[nj][reg];
          float gate = (lin*v + 0.5f*__sinf(p3*v + p4) + 0.5f*__cosf(p5*v)) * 0.25f;
          acc2[nj][reg] = (v + 0.3f*gate + 0.2f*acc3[nj][reg]) * (1.0f/1.5f);
        }
      }
    }

    // ---- nl block on odd layers ----
    if (li & 1) {
      const int j = li >> 1;
      storeC(scr, acc2, quad, l16);
      uint4 gA[8];
      loadA(gA, scr, quad, l16);
      f32x4 at[16]; zero16(at);
      gemm16<256>(gA, wsb + NL1_OFF + (size_t)j*65536, 0, at, quad, l16);
      const float* nb1p = wsf + P_NB1 + j*256;
#pragma unroll
      for (int nj = 0; nj < 16; ++nj) {
        int col = nj*16 + l16;
        float bb = nb1p[col];
#pragma unroll
        for (int reg = 0; reg < 4; ++reg)
          scr[(quad*4 + reg)*SC + col] = (bf16)tanh_fast(at[nj][reg] + bb);
      }
      uint4 tA[8];
      loadA(tA, scr, quad, l16);
      f32x4 an[16]; zero16(an);
      gemm16<256>(tA, wsb + NL2_OFF + (size_t)j*65536, 0, an, quad, l16);
      const float* nb2p = wsf + P_NB2 + j*256;
#pragma unroll
      for (int nj = 0; nj < 16; ++nj) {
        float bb = nb2p[nj*16 + l16];
#pragma unroll
        for (int reg = 0; reg < 4; ++reg) acc2[nj][reg] += 0.1f*(an[nj][reg] + bb);
      }
    }

    // ---- residual blend, L2-normalize, tanh, write back, reload curA ----
    const float alpha = (li < 4) ? 0.8f : 0.6f;
    const float beta  = 1.0f - alpha;
#pragma unroll
    for (int nj = 0; nj < 16; ++nj) {
      int col = nj*16 + l16;
#pragma unroll
      for (int reg = 0; reg < 4; ++reg) {
        float old = (float)curW[(quad*4 + reg)*SC + col];
        acc2[nj][reg] = alpha*acc2[nj][reg] + beta*old;
      }
    }
    float ra[4];
#pragma unroll
    for (int reg = 0; reg < 4; ++reg) {
      float s = 0.f;
#pragma unroll
      for (int nj = 0; nj < 16; ++nj) s += acc2[nj][reg]*acc2[nj][reg];
#pragma unroll
      for (int m = 1; m < 16; m <<= 1) s += __shfl_xor(s, m, 64);
      ra[reg] = 1.0f / (sqrtf(fmaxf(s, 0.f)) + 1e-8f);
    }
#pragma unroll
    for (int nj = 0; nj < 16; ++nj) {
      int col = nj*16 + l16;
#pragma unroll
      for (int reg = 0; reg < 4; ++reg)
        curW[(quad*4 + reg)*SC + col] = (bf16)tanh_fast(acc2[nj][reg] * ra[reg]);
    }
    loadA(curA, curW, quad, l16);
  }

  // ---- write my 16 rows (dtype matches input) ----
  if (f32io) {
    float* of = (float*)out;
#pragma unroll
    for (int it = 0; it < 16; ++it) {
      int idx = it*64 + lane;
      int row = idx >> 6, col = (idx & 63) * 4;
      const bf16* s = curW + row*SC + col;
      float4 v = make_float4((float)s[0], (float)s[1], (float)s[2], (float)s[3]);
      *(float4*)(of + (wrow + row)*Q + col) = v;
    }
  } else {
    bf16* ob = (bf16*)out;
#pragma unroll
    for (int it = 0; it < 8; ++it) {
      int idx = it*64 + lane;
      int row = idx >> 5, col = (idx & 31) * 8;
      *(uint4*)(ob + (wrow + row)*Q + col) = *(const uint4*)(curW + row*SC + col);
    }
  }
}

// ---------------- host entry ----------------
extern "C" void kernel_launch(void* const* d_in, const int* in_sizes, int n_in,
                              void* d_out, int out_size, void* d_ws, size_t ws_size,
                              hipStream_t stream) {
  const void* x    = d_in[0];
  const void* d0w1 = d_in[1];
  const void* d0b1 = d_in[2];
  const void* lnw  = d_in[3];
  const void* lnb  = d_in[4];
  const void* d0w2 = d_in[5];
  const void* d0b2 = d_in[6];
  const void* d1w1 = d_in[7];
  const void* d1b1 = d_in[8];
  const void* d1w2 = d_in[9];
  const void* d1b2 = d_in[10];
  const void* wqkv = d_in[11];
  const void* bqkv = d_in[12];
  const void* wo   = d_in[13];
  const void* bo   = d_in[14];
  const void* gp   = d_in[15];
  const void* ent  = d_in[16];
  const void* nl1  = d_in[17];
  const void* nb1  = d_in[18];
  const void* nl2  = d_in[19];
  const void* nb2  = d_in[20];

  bf16*  wsb  = (bf16*)d_ws;
  float* wsf  = (float*)((char*)d_ws + F32_BYTE_OFF);
  int*   flag = (int*)((char*)d_ws + FLAG_OFF);

  detect_dtype<<<dim3(1), dim3(256), 0, stream>>>((const uint16_t*)x, flag);
  pack_weights<<<dim3(48, 32), dim3(256), 0, stream>>>(
      d0w1, d0w2, d1w1, d1w2, wqkv, wo, ent, nl1, nl2, wsb, flag);
  pack_params<<<dim3((P_PACK_END + 255)/256), dim3(256), 0, stream>>>(
      d0b1, lnw, lnb, d0b2, d1b1, d1b2, bqkv, bo, gp, nb1, nb2, wsf, flag);
  fuse_gemm<<<dim3(1, 256, 2), dim3(256), 0, stream>>>(wsb);
  fuse_bias<<<dim3(2), dim3(256), 0, stream>>>(wsb, wsf);
  vqc_main<<<dim3(NBLK), dim3(THREADS), 0, stream>>>(x, wsb, wsf, flag, d_out);
}

// Round 10
// 1520.392 us; speedup vs baseline: 2.6110x; 2.6110x over previous
//
#include <hip/hip_runtime.h>
#include <stdint.h>

#define DI __device__ __forceinline__

typedef __bf16 bf16;
typedef __bf16 bf16x8 __attribute__((ext_vector_type(8)));
typedef float  f32x4  __attribute__((ext_vector_type(4)));

// ---------------- problem constants ----------------
constexpr int Q = 256;
constexpr int BATCH = 65536;
constexpr int TM = 128;             // rows per block (R13 geometry: best measured)
constexpr int THREADS = 512;        // 8 waves
constexpr int NW = 8;
constexpr int MT = 8;               // row-tiles per wave (128/16)
constexpr int NBLK = BATCH / TM;    // 512
constexpr int SC = Q + 8;           // LDS row stride

// ---------------- workspace layout (packed bf16 weights, Wt[N][K] row-major) ----------------
constexpr int W0A_OFF = 0;                         // 3 x (768x256)
constexpr int W0B_OFF = W0A_OFF + 3*768*256;       // 3 x (256x768)
constexpr int W1A_OFF = W0B_OFF + 3*256*768;       // 3 x (512x256)
constexpr int W1B_OFF = W1A_OFF + 3*512*256;       // 3 x (256x512)
constexpr int WV_OFF  = W1B_OFF + 3*256*512;       // 2 x (256x256)  fusion input
constexpr int WO_OFF  = WV_OFF  + 2*65536;         // 2 x (256x256)  fusion input
constexpr int ATF_OFF = WO_OFF  + 2*65536;         // 2 x (256x256)  WVO = wv@wo (packed ^T)
constexpr int ENT_OFF = ATF_OFF + 2*65536;         // 8 x (256x256)  tanh pre-applied
constexpr int NL1_OFF = ENT_OFF + 8*65536;         // 4 x (256x256)
constexpr int NL2_OFF = NL1_OFF + 4*65536;         // 4 x (256x256)
constexpr int WEND    = NL2_OFF + 4*65536;
constexpr size_t F32_BYTE_OFF = (((size_t)WEND*2) + 255) & ~(size_t)255;

// f32 param region (element offsets)
constexpr int P_D0B1 = 0;                  // 3*768
constexpr int P_LNW  = P_D0B1 + 3*768;
constexpr int P_LNB  = P_LNW  + 3*768;
constexpr int P_D0B2 = P_LNB  + 3*768;     // 3*256
constexpr int P_D1B1 = P_D0B2 + 3*256;     // 3*512
constexpr int P_D1B2 = P_D1B1 + 3*512;     // 3*256
constexpr int P_BQV  = P_D1B2 + 3*256;     // 2*256
constexpr int P_BO   = P_BQV  + 2*256;     // 2*256
constexpr int P_NB1  = P_BO   + 2*256;     // 4*256
constexpr int P_NB2  = P_NB1  + 4*256;     // 4*256
constexpr int P_GLIN = P_NB2  + 4*256;     // 8*256
constexpr int P_GP3  = P_GLIN + 8*256;
constexpr int P_GP4  = P_GP3  + 8*256;
constexpr int P_GP5  = P_GP4  + 8*256;
constexpr int P_PACK_END = P_GP5 + 8*256;  // 21,248 (filled by pack_params)
constexpr int P_BAT  = P_PACK_END;         // 2*256  fused attn bias (bqv@wo + bo)
constexpr int P_TOT  = P_BAT + 2*256;
constexpr size_t FLAG_OFF = F32_BYTE_OFF + (size_t)P_TOT*4;   // one int

// ---------------- dual-dtype load helper ----------------
DI float ldf(const void* p, size_t idx, int f32) {
  return f32 ? ((const float*)p)[idx] : (float)((const bf16*)p)[idx];
}

// ---------------- device math helpers ----------------
DI float tanh_fast(float x) {
  float ax = fabsf(x);
  float e  = __expf(-2.0f * ax);
  float r  = (1.0f - e) / (1.0f + e);
  return copysignf(r, x);
}

DI float gelu_f(float x) {   // exact-gelu via A&S 7.1.26 erf
  float ax = fabsf(x) * 0.70710678118654752f;
  float t  = 1.0f / (1.0f + 0.3275911f * ax);
  float y  = t*(0.254829592f + t*(-0.284496736f + t*(1.421413741f +
             t*(-1.453152027f + t*1.061405429f))));
  float er = copysignf(1.0f - y * __expf(-ax*ax), x);
  return 0.5f * x * (1.0f + er);
}

DI f32x4 mfma_bf16(uint4 a, uint4 b, f32x4 c) {
  return __builtin_amdgcn_mfma_f32_16x16x32_bf16(
      __builtin_bit_cast(bf16x8, a), __builtin_bit_cast(bf16x8, b), c, 0, 0, 0);
}

template<int NJ>
DI void zero_acc(f32x4 (&a)[MT][NJ]) {
#pragma unroll
  for (int i = 0; i < MT; ++i)
#pragma unroll
    for (int j = 0; j < NJ; ++j) a[i][j] = f32x4{0.f, 0.f, 0.f, 0.f};
}

// D(128 x 16*NW*NJ) += A(128x256 LDS, stride SC) * B-chunk from packed Bt[N][kdb],
// k in [koff, koff+256). n-tile index = nj*NW + wave.
// R16: HOIST = rolling B-prefetch depth (ks steps of B kept in registers).
// B load for ks+HOIST issues BEFORE the MFMAs of ks -> >=HOIST*80cy of hiding
// per load (~L2 latency at HOIST=4). Needs the waves_per_eu(2,2) 256-reg pin.
template<int NJ, int HOIST>
DI void gemm_k256(const bf16* A, const bf16* __restrict__ Bt, int kdb, int koff,
                  f32x4 (&acc)[MT][NJ], int wave, int quad, int l16) {
  const bf16* ar[MT];
#pragma unroll
  for (int mt = 0; mt < MT; ++mt) ar[mt] = A + (mt*16 + l16)*SC + quad*8;
  const bf16* br[NJ];
#pragma unroll
  for (int nj = 0; nj < NJ; ++nj)
    br[nj] = Bt + (size_t)((nj*NW + wave)*16 + l16)*kdb + koff + quad*8;
  uint4 bv[NJ][8];
#pragma unroll
  for (int ks = 0; ks < HOIST; ++ks)
#pragma unroll
    for (int nj = 0; nj < NJ; ++nj) bv[nj][ks] = *(const uint4*)(br[nj] + ks*32);
#pragma unroll
  for (int ks = 0; ks < 8; ++ks) {
    if (ks + HOIST < 8) {
#pragma unroll
      for (int nj = 0; nj < NJ; ++nj)
        bv[nj][ks + HOIST] = *(const uint4*)(br[nj] + (ks + HOIST)*32);
    }
    uint4 av[MT];
#pragma unroll
    for (int mt = 0; mt < MT; ++mt) av[mt] = *(const uint4*)(ar[mt] + ks*32);
#pragma unroll
    for (int nj = 0; nj < NJ; ++nj)
#pragma unroll
      for (int mt = 0; mt < MT; ++mt)
        acc[mt][nj] = mfma_bf16(av[mt], bv[nj][ks], acc[mt][nj]);
  }
}

// Reversed-ks variant (anti-CSE vs the forward call in dense0 pass 2).
template<int NJ, int HOIST>
DI void gemm_k256r(const bf16* A, const bf16* __restrict__ Bt, int kdb, int koff,
                   f32x4 (&acc)[MT][NJ], int wave, int quad, int l16) {
  const bf16* ar[MT];
#pragma unroll
  for (int mt = 0; mt < MT; ++mt) ar[mt] = A + (mt*16 + l16)*SC + quad*8;
  const bf16* br[NJ];
#pragma unroll
  for (int nj = 0; nj < NJ; ++nj)
    br[nj] = Bt + (size_t)((nj*NW + wave)*16 + l16)*kdb + koff + quad*8;
  uint4 bv[NJ][8];
#pragma unroll
  for (int ks = 7; ks > 7 - HOIST; --ks)
#pragma unroll
    for (int nj = 0; nj < NJ; ++nj) bv[nj][ks] = *(const uint4*)(br[nj] + ks*32);
#pragma unroll
  for (int ks = 7; ks >= 0; --ks) {
    if (ks - HOIST >= 0) {
#pragma unroll
      for (int nj = 0; nj < NJ; ++nj)
        bv[nj][ks - HOIST] = *(const uint4*)(br[nj] + (ks - HOIST)*32);
    }
    uint4 av[MT];
#pragma unroll
    for (int mt = 0; mt < MT; ++mt) av[mt] = *(const uint4*)(ar[mt] + ks*32);
#pragma unroll
    for (int nj = 0; nj < NJ; ++nj)
#pragma unroll
      for (int mt = 0; mt < MT; ++mt)
        acc[mt][nj] = mfma_bf16(av[mt], bv[nj][ks], acc[mt][nj]);
  }
}

template<int NJ>
DI void addbias(f32x4 (&a)[MT][NJ], const float* __restrict__ b, int wave, int l16) {
#pragma unroll
  for (int nj = 0; nj < NJ; ++nj) {
    float bb = b[(nj*NW + wave)*16 + l16];
#pragma unroll
    for (int mt = 0; mt < MT; ++mt)
#pragma unroll
      for (int reg = 0; reg < 4; ++reg) a[mt][nj][reg] += bb;
  }
}

template<int NJ>
DI void store_t(bf16* dst, const f32x4 (&a)[MT][NJ], int wave, int quad, int l16) {
#pragma unroll
  for (int nj = 0; nj < NJ; ++nj) {
    int col = (nj*NW + wave)*16 + l16;
#pragma unroll
    for (int mt = 0; mt < MT; ++mt)
#pragma unroll
      for (int reg = 0; reg < 4; ++reg)
        dst[(mt*16 + quad*4 + reg)*SC + col] = (bf16)a[mt][nj][reg];
  }
}

// ---------------- dtype detector ----------------
__global__ void detect_dtype(const uint16_t* __restrict__ xr, int* __restrict__ flag) {
  __shared__ int s_max;
  if (threadIdx.x == 0) s_max = 0;
  __syncthreads();
  int e = 0;
  for (int i = threadIdx.x; i < 4096; i += 256) {
    int ex = (xr[2*i] >> 7) & 0xFF;
    e = e > ex ? e : ex;
  }
  atomicMax(&s_max, e);
  __syncthreads();
  if (threadIdx.x == 0) *flag = (s_max >= 140) ? 1 : 0;
}

// ---------------- weight repack: W(KxN) -> Wt(NxK) bf16, optional tanh ----------------
__global__ void pack_weights(const void* __restrict__ d0w1, const void* __restrict__ d0w2,
                             const void* __restrict__ d1w1, const void* __restrict__ d1w2,
                             const void* __restrict__ wqkv, const void* __restrict__ wo,
                             const void* __restrict__ ent,  const void* __restrict__ nl1,
                             const void* __restrict__ nl2,  bf16* __restrict__ wsb,
                             const int* __restrict__ flag) {
  const int f32 = *flag;
  int job = blockIdx.y;
  const void* src; int mi, K, N, srcN, col0 = 0, dtanh = 0; long dst;
  if      (job < 3)  { src=d0w1; mi=job;    K=256; N=768; srcN=768; dst=W0A_OFF + (long)mi*768*256; }
  else if (job < 6)  { src=d0w2; mi=job-3;  K=768; N=256; srcN=256; dst=W0B_OFF + (long)mi*256*768; }
  else if (job < 9)  { src=d1w1; mi=job-6;  K=256; N=512; srcN=512; dst=W1A_OFF + (long)mi*512*256; }
  else if (job < 12) { src=d1w2; mi=job-9;  K=512; N=256; srcN=256; dst=W1B_OFF + (long)mi*256*512; }
  else if (job < 14) { src=wqkv; mi=job-12; K=256; N=256; srcN=768; col0=512; dst=WV_OFF + (long)mi*65536; }
  else if (job < 16) { src=wo;   mi=job-14; K=256; N=256; srcN=256; dst=WO_OFF + (long)mi*65536; }
  else if (job < 24) { src=ent;  mi=job-16; K=256; N=256; srcN=256; dst=ENT_OFF + (long)mi*65536; dtanh=1; }
  else if (job < 28) { src=nl1;  mi=job-24; K=256; N=256; srcN=256; dst=NL1_OFF + (long)mi*65536; }
  else               { src=nl2;  mi=job-28; K=256; N=256; srcN=256; dst=NL2_OFF + (long)mi*65536; }
  const size_t base = (size_t)mi * K * srcN;

  int tk = K/64, tn = N/64;
  int tile = blockIdx.x;
  if (tile >= tk*tn) return;
  int ik = tile % tk, in_ = tile / tk;

  __shared__ float t[64][65];
  int tid = threadIdx.x;
  for (int e = tid; e < 4096; e += 256) {
    int r = e >> 6, c = e & 63;
    t[r][c] = ldf(src, base + (size_t)(ik*64 + r)*srcN + col0 + in_*64 + c, f32);
  }
  __syncthreads();
  for (int e = tid; e < 4096; e += 256) {
    int nr = e >> 6, kc = e & 63;
    float v = t[kc][nr];
    if (dtanh) v = tanhf(v);
    wsb[dst + (size_t)(in_*64 + nr)*K + ik*64 + kc] = (bf16)v;
  }
}

// ---------------- param repack ----------------
__global__ void pack_params(const void* __restrict__ d0b1, const void* __restrict__ lnw,
                            const void* __restrict__ lnb,  const void* __restrict__ d0b2,
                            const void* __restrict__ d1b1, const void* __restrict__ d1b2,
                            const void* __restrict__ bqkv, const void* __restrict__ bo,
                            const void* __restrict__ gp,   const void* __restrict__ nb1,
                            const void* __restrict__ nb2,  float* __restrict__ wsf,
                            const int* __restrict__ flag) {
  const int f32 = *flag;
  int i = blockIdx.x * blockDim.x + threadIdx.x;
  if (i >= P_PACK_END) return;
  float v;
  if      (i < P_LNW)  { v = ldf(d0b1, i - P_D0B1, f32); }
  else if (i < P_LNB)  { v = ldf(lnw, i - P_LNW, f32); }
  else if (i < P_D0B2) { v = ldf(lnb, i - P_LNB, f32); }
  else if (i < P_D1B1) { v = ldf(d0b2, i - P_D0B2, f32); }
  else if (i < P_D1B2) { v = ldf(d1b1, i - P_D1B1, f32); }
  else if (i < P_BQV)  { v = ldf(d1b2, i - P_D1B2, f32); }
  else if (i < P_BO)   { int k = i - P_BQV; v = ldf(bqkv, (size_t)(k >> 8)*768 + 512 + (k & 255), f32); }
  else if (i < P_NB1)  { v = ldf(bo, i - P_BO, f32); }
  else if (i < P_NB2)  { v = ldf(nb1, i - P_NB1, f32); }
  else if (i < P_GLIN) { v = ldf(nb2, i - P_NB2, f32); }
  else if (i < P_GP3)  { int k = i - P_GLIN;
                         v = sinf(ldf(gp, (size_t)k*6 + 0, f32)) +
                             cosf(ldf(gp, (size_t)k*6 + 1, f32)) +
                             tanhf(ldf(gp, (size_t)k*6 + 2, f32)); }
  else if (i < P_GP4)  { int k = i - P_GP3; v = ldf(gp, (size_t)k*6 + 3, f32); }
  else if (i < P_GP5)  { int k = i - P_GP4; v = ldf(gp, (size_t)k*6 + 4, f32); }
  else                 { int k = i - P_GP5; v = ldf(gp, (size_t)k*6 + 5, f32); }
  wsf[i] = v;
}

// ---------------- WVO builder: ATF^T[c][m] = (wv@wo)[m][c] = sum_n wo[n][c]*wv[m][n] ----
__global__ void fuse_gemm(bf16* __restrict__ wsb) {
  int i = blockIdx.z;
  const bf16* A = wsb + WO_OFF + (size_t)i*65536;
  const bf16* B = wsb + WV_OFF + (size_t)i*65536;
  bf16* C = wsb + ATF_OFF + (size_t)i*65536;
  int m = threadIdx.x;
  int c = blockIdx.y;
  float s = 0.f;
  for (int n = 0; n < 256; ++n) s += (float)A[c*256 + n] * (float)B[(size_t)n*256 + m];
  C[(size_t)c*256 + m] = (bf16)s;
}

// ---------------- fused attn bias: P_BAT[i][c] = sum_m bqv[i][m]*woT[i][c][m] + bo[i][c] ----
__global__ void fuse_bias(const bf16* __restrict__ wsb, float* __restrict__ wsf) {
  int t = blockIdx.x * blockDim.x + threadIdx.x;
  if (t >= 512) return;
  int i = t >> 8, c = t & 255;
  const float* bqv = wsf + P_BQV + i*256;
  const bf16* woT = wsb + WO_OFF + (size_t)i*65536;
  float s = wsf[P_BO + i*256 + c];
  for (int m = 0; m < 256; ++m) s += bqv[m] * (float)woT[c*256 + m];
  wsf[P_BAT + i*256 + c] = s;
}

// ---------------- fused 8-layer forward, 128 rows/block, 8 waves ----------------
// R16 = R13 + register-pipelined B-loads:
//  - amdgpu_waves_per_eu(2,2): LDS (144 KB) already caps residency at 1 block
//    = 2 waves/SIMD, but the compiler's heuristic allocated only 128 arch VGPRs
//    (4-wave target) leaving half the register file unused and NO budget to
//    pipeline B-loads -> each of the 8 k-steps exposed a full L2 round-trip
//    (MfmaUtil 14%). The pin hands the allocator the real 256-reg budget.
//  - gemm HOIST: rolling B-prefetch 4 deep (8 where only one acc is live):
//    load bv[ks+H] before the MFMAs of ks. Worst-site ledger: acc2 64 + acs 64
//    + bv ~40 + av 32 + addr ~40 = 240 <= 256.
// R15 lesson honored: waves still SPLIT N (B streamed once per block).
__global__ __launch_bounds__(THREADS) __attribute__((amdgpu_waves_per_eu(2, 2)))
void vqc_main(const void* __restrict__ x, const bf16* __restrict__ wsb,
              const float* __restrict__ wsf, const int* __restrict__ flag,
              void* __restrict__ out) {
  __shared__ __align__(16) bf16 curT[TM*SC];   // layer input / residual (128x264)
  __shared__ __align__(16) bf16 buf0[TM*SC];   // scratch: h-chunks / t1
  __shared__ float red[2*NW*TM];               // 2048 floats
  __shared__ float rowa[TM], rowb[TM];

  const int tid  = threadIdx.x;
  const int wave = tid >> 6, lane = tid & 63;
  const int quad = lane >> 4, l16 = lane & 15;
  const size_t rowbase = (size_t)blockIdx.x * TM;
  const int f32io = *flag;

  // load x tile
  if (f32io) {
    const float* xf = (const float*)x;
    for (int i = tid; i < TM*Q/4; i += THREADS) {
      int r = i >> 6, c4 = (i & 63) * 4;
      float4 v = *(const float4*)(xf + (rowbase + r)*Q + c4);
      bf16* d = curT + r*SC + c4;
      d[0] = (bf16)v.x; d[1] = (bf16)v.y; d[2] = (bf16)v.z; d[3] = (bf16)v.w;
    }
  } else {
    const bf16* xb = (const bf16*)x;
    for (int i = tid; i < TM*Q/8; i += THREADS) {
      int r = i >> 5, c8 = (i & 31) * 8;
      *(uint4*)(curT + r*SC + c8) = *(const uint4*)(xb + (rowbase + r)*Q + c8);
    }
  }
  __syncthreads();

#pragma unroll 1
  for (int li = 0; li < 8; ++li) {
    const int t = li % 3;
    f32x4 acc2[MT][2];                     // cur_new, cols (nj*8+wave)*16+l16

    if (t == 0) {
      // ---- dense0: h = gelu(LN(cur@w1+b1)) ; cur_new = h@w2+b2 ----
      const int i = li / 3;
      const bf16* w1 = wsb + W0A_OFF + (size_t)i*768*256;
      const bf16* w2 = wsb + W0B_OFF + (size_t)i*256*768;
      const float* b1 = wsf + P_D0B1 + i*768;

      // Pass 1: LN stats, h computed chunk-wise and discarded
      float sa4[MT][4], sb4[MT][4];
#pragma unroll
      for (int mt = 0; mt < MT; ++mt)
#pragma unroll
        for (int reg = 0; reg < 4; ++reg) { sa4[mt][reg] = 0.f; sb4[mt][reg] = 0.f; }
#pragma unroll 1
      for (int c = 0; c < 3; ++c) {
        f32x4 acs[MT][2]; zero_acc<2>(acs);
        gemm_k256r<2,4>(curT, w1 + (size_t)c*256*256, 256, 0, acs, wave, quad, l16);
#pragma unroll
        for (int njl = 0; njl < 2; ++njl) {
          float bb = b1[c*256 + (njl*NW + wave)*16 + l16];
#pragma unroll
          for (int mt = 0; mt < MT; ++mt)
#pragma unroll
            for (int reg = 0; reg < 4; ++reg) {
              float v = acs[mt][njl][reg] + bb;
              sa4[mt][reg] += v; sb4[mt][reg] += v*v;
            }
        }
      }
#pragma unroll
      for (int mt = 0; mt < MT; ++mt) {
#pragma unroll
        for (int reg = 0; reg < 4; ++reg) {
          float sa = sa4[mt][reg], sb = sb4[mt][reg];
#pragma unroll
          for (int m = 1; m < 16; m <<= 1) { sa += __shfl_xor(sa, m, 64); sb += __shfl_xor(sb, m, 64); }
          if (l16 == 0) {
            int row = mt*16 + quad*4 + reg;
            red[wave*TM + row] = sa; red[NW*TM + wave*TM + row] = sb;
          }
        }
      }
      __syncthreads();
      if (tid < TM) {
        float sa = 0.f, sb = 0.f;
#pragma unroll
        for (int w = 0; w < NW; ++w) { sa += red[w*TM + tid]; sb += red[NW*TM + w*TM + tid]; }
        float mu  = sa * (1.0f/768.0f);
        float var = sb * (1.0f/768.0f) - mu*mu;
        rowa[tid] = mu; rowb[tid] = rsqrtf(fmaxf(var, 0.f) + 1e-5f);
      }
      __syncthreads();

      // Pass 2: recompute chunk, LN+gelu, GEMM2 accumulate
      zero_acc<2>(acc2);
#pragma unroll 1
      for (int c = 0; c < 3; ++c) {
        f32x4 acs[MT][2]; zero_acc<2>(acs);
        gemm_k256<2,4>(curT, w1 + (size_t)c*256*256, 256, 0, acs, wave, quad, l16);
        const float* lw = wsf + P_LNW + i*768 + c*256;
        const float* lb = wsf + P_LNB + i*768 + c*256;
#pragma unroll
        for (int njl = 0; njl < 2; ++njl) {
          int col = (njl*NW + wave)*16 + l16;
          float bb = b1[c*256 + col];
          float w_ = lw[col], lbb = lb[col];
#pragma unroll
          for (int mt = 0; mt < MT; ++mt)
#pragma unroll
            for (int reg = 0; reg < 4; ++reg) {
              int row = mt*16 + quad*4 + reg;
              float h = gelu_f((acs[mt][njl][reg] + bb - rowa[row]) * rowb[row] * w_ + lbb);
              buf0[row*SC + col] = (bf16)h;
            }
        }
        __syncthreads();
        gemm_k256<2,8>(buf0, w2, 768, 256*c, acc2, wave, quad, l16);
        __syncthreads();
      }
      addbias<2>(acc2, wsf + P_D0B2 + i*256, wave, l16);
    } else if (t == 1) {
      // ---- dense1: cur_new = silu(cur@w1+b1) @ w2 + b2, chunk-fused ----
      const int i = (li - 1) / 3;
      const bf16* w1 = wsb + W1A_OFF + (size_t)i*512*256;
      const bf16* w2 = wsb + W1B_OFF + (size_t)i*256*512;
      const float* b1 = wsf + P_D1B1 + i*512;
      zero_acc<2>(acc2);
#pragma unroll 1
      for (int c = 0; c < 2; ++c) {
        f32x4 acs[MT][2]; zero_acc<2>(acs);
        gemm_k256<2,4>(curT, w1 + (size_t)c*256*256, 256, 0, acs, wave, quad, l16);
#pragma unroll
        for (int njl = 0; njl < 2; ++njl) {
          int col = (njl*NW + wave)*16 + l16;
          float bb = b1[c*256 + col];
#pragma unroll
          for (int mt = 0; mt < MT; ++mt)
#pragma unroll
            for (int reg = 0; reg < 4; ++reg) {
              float xv = acs[mt][njl][reg] + bb;
              buf0[(mt*16 + quad*4 + reg)*SC + col] = (bf16)(xv / (1.0f + __expf(-xv)));
            }
        }
        __syncthreads();
        gemm_k256<2,8>(buf0, w2, 512, 256*c, acc2, wave, quad, l16);
        __syncthreads();
      }
      addbias<2>(acc2, wsf + P_D1B2 + i*256, wave, l16);
    } else {
      // ---- attn (collapsed): cur_new = cur@WVO + bat, single gemm, 0 barriers ----
      const int i = (li - 2) / 3;
      zero_acc<2>(acc2);
      gemm_k256<2,8>(curT, wsb + ATF_OFF + (size_t)i*65536, 256, 0, acc2, wave, quad, l16);
      addbias<2>(acc2, wsf + P_BAT + i*256, wave, l16);
    }

    // ---- entangled ----
    store_t<2>(buf0, acc2, wave, quad, l16);
    __syncthreads();
    f32x4 acc3[MT][2]; zero_acc<2>(acc3);
    gemm_k256<2,4>(buf0, wsb + ENT_OFF + (size_t)li*65536, 256, 0, acc3, wave, quad, l16);
    __syncthreads();

    // ---- gate + entangled combine ----
    const float* gl = wsf + P_GLIN + li*256;
    const float* g3 = wsf + P_GP3  + li*256;
    const float* g4 = wsf + P_GP4  + li*256;
    const float* g5 = wsf + P_GP5  + li*256;
#pragma unroll
    for (int nj = 0; nj < 2; ++nj) {
      int col = (nj*NW + wave)*16 + l16;
      float lin = gl[col], p3 = g3[col], p4 = g4[col], p5 = g5[col];
#pragma unroll
      for (int mt = 0; mt < MT; ++mt)
#pragma unroll
        for (int reg = 0; reg < 4; ++reg) {
          float v = acc2[mt][nj][reg];
          float gate = (lin*v + 0.5f*__sinf(p3*v + p4) + 0.5f*__cosf(p5*v)) * 0.25f;
          acc2[mt][nj][reg] = (v + 0.3f*gate + 0.2f*acc3[mt][nj][reg]) * (1.0f/1.5f);
        }
    }

    // ---- nl block on odd layers ----
    if (li & 1) {
      const int j = li >> 1;
      store_t<2>(buf0, acc2, wave, quad, l16);
      __syncthreads();
      f32x4 a4[MT][2]; zero_acc<2>(a4);
      gemm_k256<2,4>(buf0, wsb + NL1_OFF + (size_t)j*65536, 256, 0, a4, wave, quad, l16);
      const float* nb1p = wsf + P_NB1 + j*256;
      __syncthreads();                    // nl1 reads done -> buf0 reusable
#pragma unroll
      for (int nj = 0; nj < 2; ++nj) {
        int col = (nj*NW + wave)*16 + l16;
        float bb = nb1p[col];
#pragma unroll
        for (int mt = 0; mt < MT; ++mt)
#pragma unroll
          for (int reg = 0; reg < 4; ++reg)
            buf0[(mt*16 + quad*4 + reg)*SC + col] = (bf16)tanh_fast(a4[mt][nj][reg] + bb);
      }
      __syncthreads();
      f32x4 a5[MT][2]; zero_acc<2>(a5);
      gemm_k256<2,4>(buf0, wsb + NL2_OFF + (size_t)j*65536, 256, 0, a5, wave, quad, l16);
      const float* nb2p = wsf + P_NB2 + j*256;
#pragma unroll
      for (int nj = 0; nj < 2; ++nj) {
        float bb = nb2p[(nj*NW + wave)*16 + l16];
#pragma unroll
        for (int mt = 0; mt < MT; ++mt)
#pragma unroll
          for (int reg = 0; reg < 4; ++reg) acc2[mt][nj][reg] += 0.1f*(a5[mt][nj][reg] + bb);
      }
    }

    // ---- residual blend, L2-normalize, tanh, write back ----
    const float alpha = (li < 4) ? 0.8f : 0.6f;
    const float beta  = 1.0f - alpha;
#pragma unroll
    for (int nj = 0; nj < 2; ++nj) {
      int col = (nj*NW + wave)*16 + l16;
#pragma unroll
      for (int mt = 0; mt < MT; ++mt)
#pragma unroll
        for (int reg = 0; reg < 4; ++reg) {
          int row = mt*16 + quad*4 + reg;
          acc2[mt][nj][reg] = alpha*acc2[mt][nj][reg] + beta*(float)curT[row*SC + col];
        }
    }
#pragma unroll
    for (int mt = 0; mt < MT; ++mt) {
#pragma unroll
      for (int reg = 0; reg < 4; ++reg) {
        float s = 0.f;
#pragma unroll
        for (int nj = 0; nj < 2; ++nj) s += acc2[mt][nj][reg]*acc2[mt][nj][reg];
#pragma unroll
        for (int m = 1; m < 16; m <<= 1) s += __shfl_xor(s, m, 64);
        if (l16 == 0) red[wave*TM + mt*16 + quad*4 + reg] = s;
      }
    }
    __syncthreads();
    if (tid < TM) {
      float s = 0.f;
#pragma unroll
      for (int w = 0; w < NW; ++w) s += red[w*TM + tid];
      rowa[tid] = 1.0f / (sqrtf(fmaxf(s, 0.f)) + 1e-8f);
    }
    __syncthreads();
#pragma unroll
    for (int nj = 0; nj < 2; ++nj) {
      int col = (nj*NW + wave)*16 + l16;
#pragma unroll
      for (int mt = 0; mt < MT; ++mt)
#pragma unroll
        for (int reg = 0; reg < 4; ++reg) {
          int row = mt*16 + quad*4 + reg;
          curT[row*SC + col] = (bf16)tanh_fast(acc2[mt][nj][reg] * rowa[row]);
        }
    }
    __syncthreads();
  }

  // write result tile (dtype matches input dtype)
  if (f32io) {
    float* of = (float*)out;
    for (int i = tid; i < TM*Q/4; i += THREADS) {
      int r = i >> 6, c4 = (i & 63) * 4;
      const bf16* s = curT + r*SC + c4;
      float4 v = make_float4((float)s[0], (float)s[1], (float)s[2], (float)s[3]);
      *(float4*)(of + (rowbase + r)*Q + c4) = v;
    }
  } else {
    bf16* ob = (bf16*)out;
    for (int i = tid; i < TM*Q/8; i += THREADS) {
      int r = i >> 5, c8 = (i & 31) * 8;
      *(uint4*)(ob + (rowbase + r)*Q + c8) = *(const uint4*)(curT + r*SC + c8);
    }
  }
}

// ---------------- host entry ----------------
extern "C" void kernel_launch(void* const* d_in, const int* in_sizes, int n_in,
                              void* d_out, int out_size, void* d_ws, size_t ws_size,
                              hipStream_t stream) {
  const void* x    = d_in[0];
  const void* d0w1 = d_in[1];
  const void* d0b1 = d_in[2];
  const void* lnw  = d_in[3];
  const void* lnb  = d_in[4];
  const void* d0w2 = d_in[5];
  const void* d0b2 = d_in[6];
  const void* d1w1 = d_in[7];
  const void* d1b1 = d_in[8];
  const void* d1w2 = d_in[9];
  const void* d1b2 = d_in[10];
  const void* wqkv = d_in[11];
  const void* bqkv = d_in[12];
  const void* wo   = d_in[13];
  const void* bo   = d_in[14];
  const void* gp   = d_in[15];
  const void* ent  = d_in[16];
  const void* nl1  = d_in[17];
  const void* nb1  = d_in[18];
  const void* nl2  = d_in[19];
  const void* nb2  = d_in[20];

  bf16*  wsb  = (bf16*)d_ws;
  float* wsf  = (float*)((char*)d_ws + F32_BYTE_OFF);
  int*   flag = (int*)((char*)d_ws + FLAG_OFF);

  detect_dtype<<<dim3(1), dim3(256), 0, stream>>>((const uint16_t*)x, flag);
  pack_weights<<<dim3(48, 32), dim3(256), 0, stream>>>(
      d0w1, d0w2, d1w1, d1w2, wqkv, wo, ent, nl1, nl2, wsb, flag);
  pack_params<<<dim3((P_PACK_END + 255)/256), dim3(256), 0, stream>>>(
      d0b1, lnw, lnb, d0b2, d1b1, d1b2, bqkv, bo, gp, nb1, nb2, wsf, flag);
  fuse_gemm<<<dim3(1, 256, 2), dim3(256), 0, stream>>>(wsb);
  fuse_bias<<<dim3(2), dim3(256), 0, stream>>>(wsb, wsf);
  vqc_main<<<dim3(NBLK), dim3(THREADS), 0, stream>>>(x, wsb, wsf, flag, d_out);
}